// Round 9
// baseline (353.092 us; speedup 1.0000x reference)
//
#include <hip/hip_runtime.h>
#include <hip/hip_fp16.h>

namespace {
constexpr int Bn = 64;
constexpr int Tn = 1024;
constexpr int Kn = 256;
constexpr int TH = 512;   // merge point: fwd computes alpha(TH), bwd beta(TH)

constexpr float LOG2E  = 1.4426950408889634f;
constexpr float LN2    = 0.6931471805599453f;
constexpr float RBIAS  = 4.0f;   // headroom: p = exp2(v - (max2 + RBIAS))
constexpr float PCLAMP = 15.5f;  // f16 overflow guard (2^15.5 < 65504)

typedef _Float16 half8 __attribute__((ext_vector_type(8)));
typedef float f32x4 __attribute__((ext_vector_type(4)));

// hardware base-2 transcendentals (v_exp_f32 / v_log_f32 ARE base-2 on gfx9)
__device__ __forceinline__ float fexp2(float x) {
    float r; asm("v_exp_f32 %0, %1" : "=v"(r) : "v"(x)); return r;
}
__device__ __forceinline__ float flog2(float x) {
    float r; asm("v_log_f32 %0, %1" : "=v"(r) : "v"(x)); return r;
}

// ---- DPP wave reductions ----
template <int C>
__device__ __forceinline__ float dppmax1(float x) {
    int o = __builtin_bit_cast(int, x);
    int y = __builtin_amdgcn_update_dpp(o, o, C, 0xF, 0xF, false);
    return fmaxf(x, __builtin_bit_cast(float, y));
}
template <int C>
__device__ __forceinline__ float dppadd1(float x) {
    int y = __builtin_amdgcn_update_dpp(0, __builtin_bit_cast(int, x), C, 0xF, 0xF, true);
    return x + __builtin_bit_cast(float, y);
}
// max over a wave whose per-column values are duplicated between lanes l and l+32
__device__ __forceinline__ float wave_max32rep(float x) {
    x = dppmax1<0x111>(x);
    x = dppmax1<0x112>(x);
    x = dppmax1<0x114>(x);
    x = dppmax1<0x118>(x);
    x = dppmax1<0x142>(x);  // row_bcast:15
    return __builtin_bit_cast(float,
        __builtin_amdgcn_readlane(__builtin_bit_cast(int, x), 31));
}
__device__ __forceinline__ float wave_max64(float x) {
    x = dppmax1<0x111>(x);
    x = dppmax1<0x112>(x);
    x = dppmax1<0x114>(x);
    x = dppmax1<0x118>(x);
    x = dppmax1<0x142>(x);
    x = dppmax1<0x143>(x);
    return __builtin_bit_cast(float,
        __builtin_amdgcn_readlane(__builtin_bit_cast(int, x), 63));
}
__device__ __forceinline__ float wave_sum64(float x) {
    x = dppadd1<0x111>(x);
    x = dppadd1<0x112>(x);
    x = dppadd1<0x114>(x);
    x = dppadd1<0x118>(x);
    x = dppadd1<0x142>(x);
    x = dppadd1<0x143>(x);
    return __builtin_bit_cast(float,
        __builtin_amdgcn_readlane(__builtin_bit_cast(int, x), 63));
}
__device__ __forceinline__ float tree8(const f32x4 m0, const f32x4 m1) {
    return fmaxf(fmaxf(fmaxf(m0[0], m0[1]), fmaxf(m0[2], m0[3])),
                 fmaxf(fmaxf(m1[0], m1[1]), fmaxf(m1[2], m1[3])));
}

// ---- pre-kernel: exp(trans) fragments, fwd (E) then bwd (E^T), 8-wave layout ----
__global__ __launch_bounds__(256) void efrag_kernel(
    const float* __restrict__ trans, _Float16* __restrict__ efrag)
{
    const int g   = blockIdx.x * 256 + threadIdx.x;   // 0..16383
    const int dir = g >> 13;
    const int gg  = g & 8191;
    const int l   = gg & 63;
    const int kt  = (gg >> 6) & 7;
    const int c   = (gg >> 9) & 1;
    const int wg  = gg >> 10;
    const int n   = 32 * wg + 16 * c + (l & 15);
    const int k0  = 32 * kt + (l >> 4) * 8;
    half8 hb;
#pragma unroll
    for (int i = 0; i < 8; ++i) {
        const int k = k0 + i;
        hb[i] = (_Float16)__expf(dir == 0 ? trans[k * Kn + n]
                                          : trans[n * Kn + k]);
    }
    ((half8*)efrag)[g] = hb;
}

// A-fragment gather: batched ds_reads then REGISTER PIN so the compiler cannot
// sink the loads into the MFMA chain (R8 pathology: VGPR=96, re-read per MFMA).
#define LOAD_AF_PIN(PSH)                                                         \
    const half8* prow = (const half8*)(&PSH[PB][0]);                             \
    half8 af0 = prow[0 * 4 + La], af1 = prow[1 * 4 + La];                        \
    half8 af2 = prow[2 * 4 + La], af3 = prow[3 * 4 + La];                        \
    half8 af4 = prow[4 * 4 + La], af5 = prow[5 * 4 + La];                        \
    half8 af6 = prow[6 * 4 + La], af7 = prow[7 * 4 + La];                        \
    asm volatile("" : "+v"(af0), "+v"(af1), "+v"(af2), "+v"(af3));               \
    asm volatile("" : "+v"(af4), "+v"(af5), "+v"(af6), "+v"(af7));

#define MFMA16()                                                                 \
    f32x4 a0a = __builtin_amdgcn_mfma_f32_16x16x32_f16(af0, Bfrag[0][0], zacc, 0, 0, 0); \
    f32x4 a1a = __builtin_amdgcn_mfma_f32_16x16x32_f16(af0, Bfrag[1][0], zacc, 0, 0, 0); \
    f32x4 a0b = __builtin_amdgcn_mfma_f32_16x16x32_f16(af1, Bfrag[0][1], zacc, 0, 0, 0); \
    f32x4 a1b = __builtin_amdgcn_mfma_f32_16x16x32_f16(af1, Bfrag[1][1], zacc, 0, 0, 0); \
    a0a = __builtin_amdgcn_mfma_f32_16x16x32_f16(af2, Bfrag[0][2], a0a, 0, 0, 0); \
    a1a = __builtin_amdgcn_mfma_f32_16x16x32_f16(af2, Bfrag[1][2], a1a, 0, 0, 0); \
    a0b = __builtin_amdgcn_mfma_f32_16x16x32_f16(af3, Bfrag[0][3], a0b, 0, 0, 0); \
    a1b = __builtin_amdgcn_mfma_f32_16x16x32_f16(af3, Bfrag[1][3], a1b, 0, 0, 0); \
    a0a = __builtin_amdgcn_mfma_f32_16x16x32_f16(af4, Bfrag[0][4], a0a, 0, 0, 0); \
    a1a = __builtin_amdgcn_mfma_f32_16x16x32_f16(af4, Bfrag[1][4], a1a, 0, 0, 0); \
    a0b = __builtin_amdgcn_mfma_f32_16x16x32_f16(af5, Bfrag[0][5], a0b, 0, 0, 0); \
    a1b = __builtin_amdgcn_mfma_f32_16x16x32_f16(af5, Bfrag[1][5], a1b, 0, 0, 0); \
    a0a = __builtin_amdgcn_mfma_f32_16x16x32_f16(af6, Bfrag[0][6], a0a, 0, 0, 0); \
    a1a = __builtin_amdgcn_mfma_f32_16x16x32_f16(af6, Bfrag[1][6], a1a, 0, 0, 0); \
    a0b = __builtin_amdgcn_mfma_f32_16x16x32_f16(af7, Bfrag[0][7], a0b, 0, 0, 0); \
    a1b = __builtin_amdgcn_mfma_f32_16x16x32_f16(af7, Bfrag[1][7], a1b, 0, 0, 0); \
    const float s = (La & 1) ? (a1a[0] + a1b[0]) : (a0a[0] + a0b[0]);

// ---- forward step ----
template <int PB, int NB>
__device__ __forceinline__ void fwd_step(
    int tcur, float& alpha, float& R_prev,
    float& lg1, float& lg2, float& lg3,
    const float* __restrict__ in_b, int j_own, int La, int wg, int l,
    const half8 (&Bfrag)[2][8], const f32x4 zacc,
    _Float16 (*__restrict__ p_sh)[Kn], float (*__restrict__ Mv)[8])
{
    // --- pre-barrier: off-chain work (prefetch rotate + issue, early sum)
    const float lgC = lg1; lg1 = lg2; lg2 = lg3;
    lg3 = in_b[(size_t)(tcur + 3) * Kn + j_own];
    const float early = fmaf(lgC, LOG2E, R_prev);   // alpha = early + log2(s)

    asm volatile("s_waitcnt lgkmcnt(0)" ::: "memory");
    __builtin_amdgcn_s_barrier();
    __builtin_amdgcn_sched_barrier(0);

    // --- post-barrier: issue all LDS reads, then VALU while they fly
    LOAD_AF_PIN(p_sh)
    const f32x4 m0 = *(const f32x4*)(&Mv[NB][0]);
    const f32x4 m1 = *(const f32x4*)(&Mv[NB][4]);
    const float wmx = wave_max32rep(alpha);   // max of alpha(t-1), for t+1
    Mv[PB][wg] = wmx;
    const float R_use = tree8(m0, m1) + RBIAS;

    MFMA16()

    alpha = early + flog2(s);
    const float pv = fexp2(fminf(alpha - R_use, PCLAMP));
    if (l < 32) p_sh[NB][j_own] = (_Float16)pv;
    R_prev = R_use;
}

// ---- backward step ----
template <int PB, int NB>
__device__ __forceinline__ void bwd_step(
    int tcur, float& beta, float& x, float& R_prev,
    float& lg1, float& lg2, float& lg3,
    const float* __restrict__ in_b, int j_own, int La, int wg, int l,
    const half8 (&Bfrag)[2][8], const f32x4 zacc,
    _Float16 (*__restrict__ p_sh)[Kn], float (*__restrict__ Mv)[8])
{
    const float lgC = lg1; lg1 = lg2; lg2 = lg3;
    lg3 = in_b[(size_t)(tcur - 3) * Kn + j_own];
    const float lgC2 = lgC * LOG2E;

    asm volatile("s_waitcnt lgkmcnt(0)" ::: "memory");
    __builtin_amdgcn_s_barrier();
    __builtin_amdgcn_sched_barrier(0);

    LOAD_AF_PIN(p_sh)
    const f32x4 m0 = *(const f32x4*)(&Mv[NB][0]);
    const f32x4 m1 = *(const f32x4*)(&Mv[NB][4]);
    const float wmx = wave_max32rep(x);
    Mv[PB][wg] = wmx;
    const float R_use = tree8(m0, m1) + RBIAS;

    MFMA16()

    beta = R_prev + flog2(s);
    x = beta + lgC2;
    const float qv = fexp2(fminf(x - R_use, PCLAMP));
    if (l < 32) p_sh[NB][j_own] = (_Float16)qv;
    R_prev = R_use;
}

// ---- masked forward step (fallback path; perf-noncritical) ----
template <int PB, int NB>
__device__ __forceinline__ void m_step(
    int tcur, float& alpha, float& R_prev,
    float& lg1, float& lg2, float& lg3,
    const float* __restrict__ in_b, int j_own, int La, int wg, int l,
    const half8 (&Bfrag)[2][8], const f32x4 zacc,
    _Float16 (*__restrict__ p_sh)[Kn], float (*__restrict__ Mv)[8],
    const int* __restrict__ mask_sh)
{
    const float lgC = lg1; lg1 = lg2; lg2 = lg3;
    const int tp3 = (tcur + 3 < Tn) ? (tcur + 3) : (Tn - 1);
    lg3 = in_b[(size_t)tp3 * Kn + j_own];
    const int mkC = mask_sh[tcur];

    asm volatile("s_waitcnt lgkmcnt(0)" ::: "memory");
    __builtin_amdgcn_s_barrier();
    __builtin_amdgcn_sched_barrier(0);

    LOAD_AF_PIN(p_sh)
    const f32x4 m0 = *(const f32x4*)(&Mv[NB][0]);
    const f32x4 m1 = *(const f32x4*)(&Mv[NB][4]);
    const float wmx = wave_max32rep(alpha);
    Mv[PB][wg] = wmx;
    const float R_use = tree8(m0, m1) + RBIAS;

    MFMA16()

    const float na = R_prev + flog2(s) + lgC * LOG2E;
    if (mkC > 0) alpha = na;
    const float pv = fexp2(fminf(alpha - R_use, PCLAMP));
    if (l < 32) p_sh[NB][j_own] = (_Float16)pv;
    R_prev = R_use;
}

// ---- main kernel: one block per (chain, direction) ----
__global__ __launch_bounds__(512, 1) void crf_main(
    const float* __restrict__ inputs,     // (B,T,K)
    const long long* __restrict__ tags,   // (B,T)
    const int* __restrict__ mask,         // (B,T)
    const _Float16* __restrict__ efrag,   // exp(trans) fragments (or null)
    const float* __restrict__ trans,      // (K,K)
    const float* __restrict__ start_t,    // (K,)
    const float* __restrict__ end_t,      // (K,)
    float* __restrict__ out,              // scalar (numerator accumulated here)
    float* __restrict__ aw,               // (B,K) alpha2(TH) out
    float* __restrict__ bw)               // (B,K) beta2(TH) out
{
    const int bid = blockIdx.x;
    const int b   = bid >> 1;
    const int dir = bid & 1;         // 0 = fwd, 1 = bwd
    const int tid = threadIdx.x;
    const int wg  = tid >> 6;        // wave 0..7, owns cols [32wg, 32wg+32)
    const int l   = tid & 63;
    const int La  = l >> 4;
    const int lc  = l & 15;
    const int j_own = 32 * wg + 16 * (La & 1) + lc;  // dup on lanes l, l+32

    __shared__ __align__(16) _Float16 p_sh[2][Kn];
    __shared__ __align__(16) float Mv[2][8];
    __shared__ int   mask_sh[Tn];
    __shared__ float sh_np;
    __shared__ int   sh_len;

    if (tid == 0) { sh_len = 0; sh_np = 0.f; }

    // ---- stage mask + length
    int cnt = 0;
    for (int t = tid; t < Tn; t += 512) {
        const int m = mask[b * Tn + t];
        mask_sh[t] = m;
        cnt += (m > 0) ? 1 : 0;
    }
    __syncthreads();
    {
        const float cf = wave_sum64((float)cnt);
        if (l == 0) atomicAdd(&sh_len, (int)(cf + 0.5f));
    }

    // ---- B-fragments: E for fwd, E^T for bwd
    half8 Bfrag[2][8];
    if (efrag != nullptr) {
        const half8* ef = (const half8*)efrag;
        const int base = dir * 8192;
#pragma unroll
        for (int c = 0; c < 2; ++c)
#pragma unroll
            for (int kt = 0; kt < 8; ++kt)
                Bfrag[c][kt] = ef[base + ((wg * 2 + c) * 8 + kt) * 64 + l];
    } else {
#pragma unroll
        for (int c = 0; c < 2; ++c) {
            const int n = 32 * wg + 16 * c + lc;
#pragma unroll
            for (int kt = 0; kt < 8; ++kt) {
                const int k0 = 32 * kt + La * 8;
                half8 hb;
#pragma unroll
                for (int i = 0; i < 8; ++i) {
                    const int k = k0 + i;
                    hb[i] = (_Float16)__expf(dir == 0 ? trans[k * Kn + n]
                                                      : trans[n * Kn + k]);
                }
                Bfrag[c][kt] = hb;
            }
        }
    }

    const size_t bTK = (size_t)b * (size_t)(Tn * Kn);
    const float* in_b = inputs + bTK;
    const float endj  = end_t[j_own];

    f32x4 zacc = {0.f, 0.f, 0.f, 0.f};
    asm volatile("" : "+v"(zacc));

    // ---- direction-specific init
    float alpha = 0.f, beta = 0.f, x = 0.f;
    float lg1 = 0.f, lg2 = 0.f, lg3 = 0.f;
    if (dir == 0) {
        alpha = (in_b[j_own] + start_t[j_own]) * LOG2E;
        lg1 = in_b[1 * Kn + j_own];
        lg2 = in_b[2 * Kn + j_own];
        lg3 = in_b[3 * Kn + j_own];
        Mv[1][wg] = wave_max32rep(alpha);
    } else {
        beta = endj * LOG2E;
        x    = beta + in_b[(size_t)(Tn - 1) * Kn + j_own] * LOG2E;
        lg1 = in_b[(size_t)(Tn - 2) * Kn + j_own];
        lg2 = in_b[(size_t)(Tn - 3) * Kn + j_own];
        lg3 = in_b[(size_t)(Tn - 4) * Kn + j_own];
        Mv[1][wg] = wave_max32rep(x);
    }
    __syncthreads();
    const int end_idx = sh_len - 1;

    float R_prev;
    {
        const f32x4 m0 = *(const f32x4*)(&Mv[1][0]);
        const f32x4 m1 = *(const f32x4*)(&Mv[1][4]);
        R_prev = tree8(m0, m1) + RBIAS;
        const float v0 = (dir == 0) ? alpha : x;
        const float pv = fexp2(fminf(v0 - R_prev, PCLAMP));
        if (l < 32) p_sh[0][j_own] = (_Float16)pv;
    }

    if (sh_len == Tn) {
        if (dir == 0) {
            // fwd: steps t = 1..512 -> alpha2(512)
            for (int t = 1; t <= TH; t += 2) {
                fwd_step<0, 1>(t,     alpha, R_prev, lg1, lg2, lg3,
                               in_b, j_own, La, wg, l, Bfrag, zacc, p_sh, Mv);
                fwd_step<1, 0>(t + 1, alpha, R_prev, lg1, lg2, lg3,
                               in_b, j_own, La, wg, l, Bfrag, zacc, p_sh, Mv);
            }
            if (l < 32) aw[b * Kn + j_own] = alpha;
        } else {
            // bwd: steps tcur = 1022..512 (511 steps) -> beta2(512)
            bwd_step<0, 1>(1022, beta, x, R_prev, lg1, lg2, lg3,
                           in_b, j_own, La, wg, l, Bfrag, zacc, p_sh, Mv);
            for (int t = 1021; t >= 513; t -= 2) {
                bwd_step<1, 0>(t,     beta, x, R_prev, lg1, lg2, lg3,
                               in_b, j_own, La, wg, l, Bfrag, zacc, p_sh, Mv);
                bwd_step<0, 1>(t - 1, beta, x, R_prev, lg1, lg2, lg3,
                               in_b, j_own, La, wg, l, Bfrag, zacc, p_sh, Mv);
            }
            if (l < 32) bw[b * Kn + j_own] = beta;
        }
    } else {
        if (dir == 0) {
            // masked fallback: full 1023-step chain; fold end_t before writing
            m_step<0, 1>(1, alpha, R_prev, lg1, lg2, lg3, in_b, j_own, La, wg, l,
                         Bfrag, zacc, p_sh, Mv, mask_sh);
            for (int t = 2; t < Tn; t += 2) {
                m_step<1, 0>(t,     alpha, R_prev, lg1, lg2, lg3, in_b, j_own, La,
                             wg, l, Bfrag, zacc, p_sh, Mv, mask_sh);
                m_step<0, 1>(t + 1, alpha, R_prev, lg1, lg2, lg3, in_b, j_own, La,
                             wg, l, Bfrag, zacc, p_sh, Mv, mask_sh);
            }
            if (l < 32) aw[b * Kn + j_own] = alpha + endj * LOG2E;
        } else {
            // masked bwd: identity contribution
            if (tid < Kn) bw[b * Kn + tid] = 0.f;
            return;
        }
    }

    // ---- numerator: fwd block only
    if (dir == 0) {
        float np = 0.f;
        for (int t = tid; t < Tn; t += 512) {
            const int   tg = (int)tags[b * Tn + t];
            const float e  = in_b[(size_t)t * Kn + tg];
            if (t == 0) {
                np += e + start_t[tg];
            } else {
                const float mf = (float)mask_sh[t];
                const int   tq = (int)tags[b * Tn + t - 1];
                np += mf * (e + trans[tq * Kn + tg]);
            }
        }
        np = wave_sum64(np);
        if (l == 0) atomicAdd(&sh_np, np);
        __syncthreads();
        if (tid == 0) {
            atomicAdd(out, sh_np + end_t[(int)tags[b * Tn + end_idx]]);
        }
    }
}

// ---- merge kernel: denom_b = ln2 * LSE2_j(alpha2[b][j] + beta2[b][j]) ----
__global__ __launch_bounds__(64) void merge_kernel(
    const float* __restrict__ aw, const float* __restrict__ bw,
    float* __restrict__ out)
{
    const int b = blockIdx.x;
    const int l = threadIdx.x;
    const f32x4 va = *(const f32x4*)(aw + b * Kn + 4 * l);
    const f32x4 vb = *(const f32x4*)(bw + b * Kn + 4 * l);
    const float v0 = va[0] + vb[0];
    const float v1 = va[1] + vb[1];
    const float v2 = va[2] + vb[2];
    const float v3 = va[3] + vb[3];
    float m = fmaxf(fmaxf(v0, v1), fmaxf(v2, v3));
    m = wave_max64(m);
    float S = fexp2(v0 - m) + fexp2(v1 - m) + fexp2(v2 - m) + fexp2(v3 - m);
    S = wave_sum64(S);
    if (l == 0) atomicAdd(out, -(LN2 * (m + flog2(S))));
}

}  // namespace

extern "C" void kernel_launch(void* const* d_in, const int* in_sizes, int n_in,
                              void* d_out, int out_size, void* d_ws, size_t ws_size,
                              hipStream_t stream) {
    const float*     inputs  = (const float*)d_in[0];
    const long long* tags    = (const long long*)d_in[1];
    const int*       mask    = (const int*)d_in[2];
    const float*     trans   = (const float*)d_in[3];
    const float*     start_t = (const float*)d_in[4];
    const float*     end_t   = (const float*)d_in[5];
    float* out = (float*)d_out;

    // workspace layout: aw (B*K f32) | bw (B*K f32) | efrag (2*K*K f16)
    float*    aw = (float*)d_ws;
    float*    bw = aw + Bn * Kn;
    _Float16* ef = (_Float16*)(bw + Bn * Kn);
    const size_t need_vec = (size_t)2 * Bn * Kn * sizeof(float);          // 128 KiB
    const size_t need_ef  = need_vec + (size_t)2 * Kn * Kn * sizeof(_Float16);
    const bool useEf = (d_ws != nullptr) && (ws_size >= need_ef);

    (void)hipMemsetAsync(out, 0, sizeof(float), stream);
    if (useEf) {
        efrag_kernel<<<dim3((2 * Kn * Kn / 8) / 256), dim3(256), 0, stream>>>(
            trans, ef);
    }
    crf_main<<<dim3(2 * Bn), dim3(512), 0, stream>>>(
        inputs, tags, mask, useEf ? (const _Float16*)ef : nullptr,
        trans, start_t, end_t, out, aw, bw);
    merge_kernel<<<dim3(Bn), dim3(64), 0, stream>>>(aw, bw, out);
}

// Round 10
// 335.863 us; speedup vs baseline: 1.0513x; 1.0513x over previous
//
#include <hip/hip_runtime.h>
#include <hip/hip_fp16.h>

namespace {
constexpr int Bn = 64;
constexpr int Tn = 1024;
constexpr int Kn = 256;
constexpr int TH = 512;   // merge point: fwd computes alpha(TH), bwd beta(TH)

constexpr float LOG2E  = 1.4426950408889634f;
constexpr float LN2    = 0.6931471805599453f;
constexpr float RBIAS  = 4.0f;   // headroom: p = exp2(v - (max2 + RBIAS))
constexpr float PCLAMP = 15.5f;  // f16 overflow guard (2^15.5 < 65504)

typedef _Float16 half8 __attribute__((ext_vector_type(8)));
typedef float f32x4 __attribute__((ext_vector_type(4)));

// hardware base-2 transcendentals (v_exp_f32 / v_log_f32 ARE base-2 on gfx9)
__device__ __forceinline__ float fexp2(float x) {
    float r; asm("v_exp_f32 %0, %1" : "=v"(r) : "v"(x)); return r;
}
__device__ __forceinline__ float flog2(float x) {
    float r; asm("v_log_f32 %0, %1" : "=v"(r) : "v"(x)); return r;
}

// ---- DPP wave reductions ----
template <int C>
__device__ __forceinline__ float dppmax1(float x) {
    int o = __builtin_bit_cast(int, x);
    int y = __builtin_amdgcn_update_dpp(o, o, C, 0xF, 0xF, false);
    return fmaxf(x, __builtin_bit_cast(float, y));
}
template <int C>
__device__ __forceinline__ float dppadd1(float x) {
    int y = __builtin_amdgcn_update_dpp(0, __builtin_bit_cast(int, x), C, 0xF, 0xF, true);
    return x + __builtin_bit_cast(float, y);
}
__device__ __forceinline__ float wave_max64(float x) {
    x = dppmax1<0x111>(x);
    x = dppmax1<0x112>(x);
    x = dppmax1<0x114>(x);
    x = dppmax1<0x118>(x);
    x = dppmax1<0x142>(x);  // row_bcast:15
    x = dppmax1<0x143>(x);  // row_bcast:31
    return __builtin_bit_cast(float,
        __builtin_amdgcn_readlane(__builtin_bit_cast(int, x), 63));
}
__device__ __forceinline__ float wave_sum64(float x) {
    x = dppadd1<0x111>(x);
    x = dppadd1<0x112>(x);
    x = dppadd1<0x114>(x);
    x = dppadd1<0x118>(x);
    x = dppadd1<0x142>(x);
    x = dppadd1<0x143>(x);
    return __builtin_bit_cast(float,
        __builtin_amdgcn_readlane(__builtin_bit_cast(int, x), 63));
}
__device__ __forceinline__ float tree4(const f32x4 m) {
    return fmaxf(fmaxf(m[0], m[1]), fmaxf(m[2], m[3]));
}

// ---- pre-kernel: exp(trans) fragments, fwd (E) then bwd (E^T), 4-wave layout ----
// wave wg (0..3) owns cols [64wg, 64wg+64) = 4 N-tiles. Tile c:
// n = 64wg + 16c + (l&15); k = 32kt + (l>>4)*8 + i.
// flat half8 idx g = dir*8192 + ((wg*4 + c)*8 + kt)*64 + l
__global__ __launch_bounds__(256) void efrag_kernel(
    const float* __restrict__ trans, _Float16* __restrict__ efrag)
{
    const int g   = blockIdx.x * 256 + threadIdx.x;   // 0..16383
    const int dir = g >> 13;
    const int gg  = g & 8191;
    const int l   = gg & 63;
    const int kt  = (gg >> 6) & 7;
    const int c   = (gg >> 9) & 3;
    const int wg  = (gg >> 11) & 3;
    const int n   = 64 * wg + 16 * c + (l & 15);
    const int k0  = 32 * kt + (l >> 4) * 8;
    half8 hb;
#pragma unroll
    for (int i = 0; i < 8; ++i) {
        const int k = k0 + i;
        hb[i] = (_Float16)__expf(dir == 0 ? trans[k * Kn + n]
                                          : trans[n * Kn + k]);
    }
    ((half8*)efrag)[g] = hb;
}

// 4-chain MFMA over the wave's 4 N-tiles, full K=256; af reused across tiles.
// Result: s = this lane's own column's sum (col j_own = 64wg + l).
#define MFMA32_SELECT()                                                          \
    const half8* prow = (const half8*)(&p_sh[PB][0]);                            \
    half8 af0 = prow[0 * 4 + La], af1 = prow[1 * 4 + La];                        \
    half8 af2 = prow[2 * 4 + La], af3 = prow[3 * 4 + La];                        \
    half8 af4 = prow[4 * 4 + La], af5 = prow[5 * 4 + La];                        \
    half8 af6 = prow[6 * 4 + La], af7 = prow[7 * 4 + La];                        \
    f32x4 a0 = __builtin_amdgcn_mfma_f32_16x16x32_f16(af0, Bfrag[0][0], zacc, 0, 0, 0); \
    f32x4 a1 = __builtin_amdgcn_mfma_f32_16x16x32_f16(af0, Bfrag[1][0], zacc, 0, 0, 0); \
    f32x4 a2 = __builtin_amdgcn_mfma_f32_16x16x32_f16(af0, Bfrag[2][0], zacc, 0, 0, 0); \
    f32x4 a3 = __builtin_amdgcn_mfma_f32_16x16x32_f16(af0, Bfrag[3][0], zacc, 0, 0, 0); \
    a0 = __builtin_amdgcn_mfma_f32_16x16x32_f16(af1, Bfrag[0][1], a0, 0, 0, 0);  \
    a1 = __builtin_amdgcn_mfma_f32_16x16x32_f16(af1, Bfrag[1][1], a1, 0, 0, 0);  \
    a2 = __builtin_amdgcn_mfma_f32_16x16x32_f16(af1, Bfrag[2][1], a2, 0, 0, 0);  \
    a3 = __builtin_amdgcn_mfma_f32_16x16x32_f16(af1, Bfrag[3][1], a3, 0, 0, 0);  \
    a0 = __builtin_amdgcn_mfma_f32_16x16x32_f16(af2, Bfrag[0][2], a0, 0, 0, 0);  \
    a1 = __builtin_amdgcn_mfma_f32_16x16x32_f16(af2, Bfrag[1][2], a1, 0, 0, 0);  \
    a2 = __builtin_amdgcn_mfma_f32_16x16x32_f16(af2, Bfrag[2][2], a2, 0, 0, 0);  \
    a3 = __builtin_amdgcn_mfma_f32_16x16x32_f16(af2, Bfrag[3][2], a3, 0, 0, 0);  \
    a0 = __builtin_amdgcn_mfma_f32_16x16x32_f16(af3, Bfrag[0][3], a0, 0, 0, 0);  \
    a1 = __builtin_amdgcn_mfma_f32_16x16x32_f16(af3, Bfrag[1][3], a1, 0, 0, 0);  \
    a2 = __builtin_amdgcn_mfma_f32_16x16x32_f16(af3, Bfrag[2][3], a2, 0, 0, 0);  \
    a3 = __builtin_amdgcn_mfma_f32_16x16x32_f16(af3, Bfrag[3][3], a3, 0, 0, 0);  \
    a0 = __builtin_amdgcn_mfma_f32_16x16x32_f16(af4, Bfrag[0][4], a0, 0, 0, 0);  \
    a1 = __builtin_amdgcn_mfma_f32_16x16x32_f16(af4, Bfrag[1][4], a1, 0, 0, 0);  \
    a2 = __builtin_amdgcn_mfma_f32_16x16x32_f16(af4, Bfrag[2][4], a2, 0, 0, 0);  \
    a3 = __builtin_amdgcn_mfma_f32_16x16x32_f16(af4, Bfrag[3][4], a3, 0, 0, 0);  \
    a0 = __builtin_amdgcn_mfma_f32_16x16x32_f16(af5, Bfrag[0][5], a0, 0, 0, 0);  \
    a1 = __builtin_amdgcn_mfma_f32_16x16x32_f16(af5, Bfrag[1][5], a1, 0, 0, 0);  \
    a2 = __builtin_amdgcn_mfma_f32_16x16x32_f16(af5, Bfrag[2][5], a2, 0, 0, 0);  \
    a3 = __builtin_amdgcn_mfma_f32_16x16x32_f16(af5, Bfrag[3][5], a3, 0, 0, 0);  \
    a0 = __builtin_amdgcn_mfma_f32_16x16x32_f16(af6, Bfrag[0][6], a0, 0, 0, 0);  \
    a1 = __builtin_amdgcn_mfma_f32_16x16x32_f16(af6, Bfrag[1][6], a1, 0, 0, 0);  \
    a2 = __builtin_amdgcn_mfma_f32_16x16x32_f16(af6, Bfrag[2][6], a2, 0, 0, 0);  \
    a3 = __builtin_amdgcn_mfma_f32_16x16x32_f16(af6, Bfrag[3][6], a3, 0, 0, 0);  \
    a0 = __builtin_amdgcn_mfma_f32_16x16x32_f16(af7, Bfrag[0][7], a0, 0, 0, 0);  \
    a1 = __builtin_amdgcn_mfma_f32_16x16x32_f16(af7, Bfrag[1][7], a1, 0, 0, 0);  \
    a2 = __builtin_amdgcn_mfma_f32_16x16x32_f16(af7, Bfrag[2][7], a2, 0, 0, 0);  \
    a3 = __builtin_amdgcn_mfma_f32_16x16x32_f16(af7, Bfrag[3][7], a3, 0, 0, 0);  \
    const float s01 = (La & 1) ? a1[0] : a0[0];                                  \
    const float s23 = (La & 1) ? a3[0] : a2[0];                                  \
    const float s   = (La & 2) ? s23 : s01;

// ---- forward step ----
template <int PB, int NB>
__device__ __forceinline__ void fwd_step(
    int tcur, float& alpha, float& R_prev,
    float& lg1, float& lg2, float& lg3,
    const float* __restrict__ in_b, int j_own, int La, int wg,
    const half8 (&Bfrag)[4][8], const f32x4 zacc,
    _Float16 (*__restrict__ p_sh)[Kn], float (*__restrict__ Mv)[4])
{
    // pre-barrier: off-chain work (prefetch rotate + issue, early fma)
    const float lgC = lg1; lg1 = lg2; lg2 = lg3;
    lg3 = in_b[(size_t)(tcur + 3) * Kn + j_own];
    const float early = fmaf(lgC, LOG2E, R_prev);   // alpha = early + log2(s)

    asm volatile("s_waitcnt lgkmcnt(0)" ::: "memory");
    __builtin_amdgcn_s_barrier();
    __builtin_amdgcn_sched_barrier(0);

    const f32x4 mv = *(const f32x4*)(&Mv[NB][0]);     // broadcast read
    const float wmx = wave_max64(alpha);              // max alpha(t-1), for t+1
    Mv[PB][wg] = wmx;
    const float R_use = tree4(mv) + RBIAS;

    MFMA32_SELECT()

    alpha = early + flog2(s);
    const float pv = fexp2(fminf(alpha - R_use, PCLAMP));
    p_sh[NB][j_own] = (_Float16)pv;                   // each lane: own column
    R_prev = R_use;
}

// ---- backward step ----
template <int PB, int NB>
__device__ __forceinline__ void bwd_step(
    int tcur, float& beta, float& x, float& R_prev,
    float& lg1, float& lg2, float& lg3,
    const float* __restrict__ in_b, int j_own, int La, int wg,
    const half8 (&Bfrag)[4][8], const f32x4 zacc,
    _Float16 (*__restrict__ p_sh)[Kn], float (*__restrict__ Mv)[4])
{
    const float lgC = lg1; lg1 = lg2; lg2 = lg3;
    lg3 = in_b[(size_t)(tcur - 3) * Kn + j_own];
    const float lgC2 = lgC * LOG2E;

    asm volatile("s_waitcnt lgkmcnt(0)" ::: "memory");
    __builtin_amdgcn_s_barrier();
    __builtin_amdgcn_sched_barrier(0);

    const f32x4 mv = *(const f32x4*)(&Mv[NB][0]);
    const float wmx = wave_max64(x);
    Mv[PB][wg] = wmx;
    const float R_use = tree4(mv) + RBIAS;

    MFMA32_SELECT()

    beta = R_prev + flog2(s);
    x = beta + lgC2;
    const float qv = fexp2(fminf(x - R_use, PCLAMP));
    p_sh[NB][j_own] = (_Float16)qv;
    R_prev = R_use;
}

// ---- masked forward step (fallback path; perf-noncritical) ----
template <int PB, int NB>
__device__ __forceinline__ void m_step(
    int tcur, float& alpha, float& R_prev,
    float& lg1, float& lg2, float& lg3,
    const float* __restrict__ in_b, int j_own, int La, int wg,
    const half8 (&Bfrag)[4][8], const f32x4 zacc,
    _Float16 (*__restrict__ p_sh)[Kn], float (*__restrict__ Mv)[4],
    const int* __restrict__ mask_sh)
{
    const float lgC = lg1; lg1 = lg2; lg2 = lg3;
    const int tp3 = (tcur + 3 < Tn) ? (tcur + 3) : (Tn - 1);
    lg3 = in_b[(size_t)tp3 * Kn + j_own];
    const int mkC = mask_sh[tcur];

    asm volatile("s_waitcnt lgkmcnt(0)" ::: "memory");
    __builtin_amdgcn_s_barrier();
    __builtin_amdgcn_sched_barrier(0);

    const f32x4 mv = *(const f32x4*)(&Mv[NB][0]);
    const float wmx = wave_max64(alpha);
    Mv[PB][wg] = wmx;
    const float R_use = tree4(mv) + RBIAS;

    MFMA32_SELECT()

    const float na = R_prev + flog2(s) + lgC * LOG2E;
    if (mkC > 0) alpha = na;
    const float pv = fexp2(fminf(alpha - R_use, PCLAMP));
    p_sh[NB][j_own] = (_Float16)pv;
    R_prev = R_use;
}

// ---- main kernel: one block per (chain, direction); 4 waves ----
__global__ __launch_bounds__(256, 1) void crf_main(
    const float* __restrict__ inputs,     // (B,T,K)
    const long long* __restrict__ tags,   // (B,T)
    const int* __restrict__ mask,         // (B,T)
    const _Float16* __restrict__ efrag,   // exp(trans) fragments (or null)
    const float* __restrict__ trans,      // (K,K)
    const float* __restrict__ start_t,    // (K,)
    const float* __restrict__ end_t,      // (K,)
    float* __restrict__ out,              // scalar (numerator accumulated here)
    float* __restrict__ aw,               // (B,K) alpha2(TH) out
    float* __restrict__ bw)               // (B,K) beta2(TH) out
{
    const int bid = blockIdx.x;
    const int b   = bid >> 1;
    const int dir = bid & 1;         // 0 = fwd, 1 = bwd
    const int tid = threadIdx.x;
    const int wg  = tid >> 6;        // wave 0..3, owns cols [64wg, 64wg+64)
    const int l   = tid & 63;
    const int La  = l >> 4;          // 0..3 (k-slice group / tile select)
    const int j_own = 64 * wg + l;   // every lane owns exactly one column

    __shared__ __align__(16) _Float16 p_sh[2][Kn];
    __shared__ __align__(16) float Mv[2][4];
    __shared__ int   mask_sh[Tn];
    __shared__ float sh_np;
    __shared__ int   sh_len;

    if (tid == 0) { sh_len = 0; sh_np = 0.f; }

    // ---- stage mask + length
    int cnt = 0;
    for (int t = tid; t < Tn; t += 256) {
        const int m = mask[b * Tn + t];
        mask_sh[t] = m;
        cnt += (m > 0) ? 1 : 0;
    }
    __syncthreads();
    {
        const float cf = wave_sum64((float)cnt);
        if (l == 0) atomicAdd(&sh_len, (int)(cf + 0.5f));
    }

    // ---- B-fragments: E for fwd, E^T for bwd; 4 N-tiles per wave
    half8 Bfrag[4][8];
    if (efrag != nullptr) {
        const half8* ef = (const half8*)efrag;
        const int base = dir * 8192;
#pragma unroll
        for (int c = 0; c < 4; ++c)
#pragma unroll
            for (int kt = 0; kt < 8; ++kt)
                Bfrag[c][kt] = ef[base + ((wg * 4 + c) * 8 + kt) * 64 + l];
    } else {
#pragma unroll
        for (int c = 0; c < 4; ++c) {
            const int n = 64 * wg + 16 * c + (l & 15);
#pragma unroll
            for (int kt = 0; kt < 8; ++kt) {
                const int k0 = 32 * kt + La * 8;
                half8 hb;
#pragma unroll
                for (int i = 0; i < 8; ++i) {
                    const int k = k0 + i;
                    hb[i] = (_Float16)__expf(dir == 0 ? trans[k * Kn + n]
                                                      : trans[n * Kn + k]);
                }
                Bfrag[c][kt] = hb;
            }
        }
    }

    const size_t bTK = (size_t)b * (size_t)(Tn * Kn);
    const float* in_b = inputs + bTK;
    const float endj  = end_t[j_own];

    f32x4 zacc = {0.f, 0.f, 0.f, 0.f};
    asm volatile("" : "+v"(zacc));

    // ---- direction-specific init (own column only)
    float alpha = 0.f, beta = 0.f, x = 0.f;
    float lg1 = 0.f, lg2 = 0.f, lg3 = 0.f;
    if (dir == 0) {
        alpha = (in_b[j_own] + start_t[j_own]) * LOG2E;
        lg1 = in_b[1 * Kn + j_own];
        lg2 = in_b[2 * Kn + j_own];
        lg3 = in_b[3 * Kn + j_own];
        Mv[1][wg] = wave_max64(alpha);
    } else {
        beta = endj * LOG2E;
        x    = beta + in_b[(size_t)(Tn - 1) * Kn + j_own] * LOG2E;
        lg1 = in_b[(size_t)(Tn - 2) * Kn + j_own];
        lg2 = in_b[(size_t)(Tn - 3) * Kn + j_own];
        lg3 = in_b[(size_t)(Tn - 4) * Kn + j_own];
        Mv[1][wg] = wave_max64(x);
    }
    __syncthreads();
    const int end_idx = sh_len - 1;

    float R_prev;
    {
        R_prev = tree4(*(const f32x4*)(&Mv[1][0])) + RBIAS;
        const float v0 = (dir == 0) ? alpha : x;
        const float pv = fexp2(fminf(v0 - R_prev, PCLAMP));
        p_sh[0][j_own] = (_Float16)pv;
    }

    if (sh_len == Tn) {
        if (dir == 0) {
            // fwd: steps t = 1..512 -> alpha2(512)
            for (int t = 1; t <= TH; t += 2) {
                fwd_step<0, 1>(t,     alpha, R_prev, lg1, lg2, lg3,
                               in_b, j_own, La, wg, Bfrag, zacc, p_sh, Mv);
                fwd_step<1, 0>(t + 1, alpha, R_prev, lg1, lg2, lg3,
                               in_b, j_own, La, wg, Bfrag, zacc, p_sh, Mv);
            }
            aw[b * Kn + j_own] = alpha;
        } else {
            // bwd: steps tcur = 1022..512 (511 steps) -> beta2(512)
            bwd_step<0, 1>(1022, beta, x, R_prev, lg1, lg2, lg3,
                           in_b, j_own, La, wg, Bfrag, zacc, p_sh, Mv);
            for (int t = 1021; t >= 513; t -= 2) {
                bwd_step<1, 0>(t,     beta, x, R_prev, lg1, lg2, lg3,
                               in_b, j_own, La, wg, Bfrag, zacc, p_sh, Mv);
                bwd_step<0, 1>(t - 1, beta, x, R_prev, lg1, lg2, lg3,
                               in_b, j_own, La, wg, Bfrag, zacc, p_sh, Mv);
            }
            bw[b * Kn + j_own] = beta;
        }
    } else {
        if (dir == 0) {
            // masked fallback: full 1023-step chain; fold end_t before writing
            m_step<0, 1>(1, alpha, R_prev, lg1, lg2, lg3, in_b, j_own, La, wg,
                         Bfrag, zacc, p_sh, Mv, mask_sh);
            for (int t = 2; t < Tn; t += 2) {
                m_step<1, 0>(t,     alpha, R_prev, lg1, lg2, lg3, in_b, j_own, La,
                             wg, Bfrag, zacc, p_sh, Mv, mask_sh);
                m_step<0, 1>(t + 1, alpha, R_prev, lg1, lg2, lg3, in_b, j_own, La,
                             wg, Bfrag, zacc, p_sh, Mv, mask_sh);
            }
            aw[b * Kn + j_own] = alpha + endj * LOG2E;
        } else {
            // masked bwd: identity contribution
            bw[b * Kn + tid] = 0.f;
            return;
        }
    }

    // ---- numerator: fwd block only
    if (dir == 0) {
        float np = 0.f;
        for (int t = tid; t < Tn; t += 256) {
            const int   tg = (int)tags[b * Tn + t];
            const float e  = in_b[(size_t)t * Kn + tg];
            if (t == 0) {
                np += e + start_t[tg];
            } else {
                const float mf = (float)mask_sh[t];
                const int   tq = (int)tags[b * Tn + t - 1];
                np += mf * (e + trans[tq * Kn + tg]);
            }
        }
        np = wave_sum64(np);
        if (l == 0) atomicAdd(&sh_np, np);
        __syncthreads();
        if (tid == 0) {
            atomicAdd(out, sh_np + end_t[(int)tags[b * Tn + end_idx]]);
        }
    }
}

// ---- merge kernel: denom_b = ln2 * LSE2_j(alpha2[b][j] + beta2[b][j]) ----
__global__ __launch_bounds__(64) void merge_kernel(
    const float* __restrict__ aw, const float* __restrict__ bw,
    float* __restrict__ out)
{
    const int b = blockIdx.x;
    const int l = threadIdx.x;
    const f32x4 va = *(const f32x4*)(aw + b * Kn + 4 * l);
    const f32x4 vb = *(const f32x4*)(bw + b * Kn + 4 * l);
    const float v0 = va[0] + vb[0];
    const float v1 = va[1] + vb[1];
    const float v2 = va[2] + vb[2];
    const float v3 = va[3] + vb[3];
    float m = fmaxf(fmaxf(v0, v1), fmaxf(v2, v3));
    m = wave_max64(m);
    float S = fexp2(v0 - m) + fexp2(v1 - m) + fexp2(v2 - m) + fexp2(v3 - m);
    S = wave_sum64(S);
    if (l == 0) atomicAdd(out, -(LN2 * (m + flog2(S))));
}

}  // namespace

extern "C" void kernel_launch(void* const* d_in, const int* in_sizes, int n_in,
                              void* d_out, int out_size, void* d_ws, size_t ws_size,
                              hipStream_t stream) {
    const float*     inputs  = (const float*)d_in[0];
    const long long* tags    = (const long long*)d_in[1];
    const int*       mask    = (const int*)d_in[2];
    const float*     trans   = (const float*)d_in[3];
    const float*     start_t = (const float*)d_in[4];
    const float*     end_t   = (const float*)d_in[5];
    float* out = (float*)d_out;

    // workspace layout: aw (B*K f32) | bw (B*K f32) | efrag (2*K*K f16)
    float*    aw = (float*)d_ws;
    float*    bw = aw + Bn * Kn;
    _Float16* ef = (_Float16*)(bw + Bn * Kn);
    const size_t need_vec = (size_t)2 * Bn * Kn * sizeof(float);          // 128 KiB
    const size_t need_ef  = need_vec + (size_t)2 * Kn * Kn * sizeof(_Float16);
    const bool useEf = (d_ws != nullptr) && (ws_size >= need_ef);

    (void)hipMemsetAsync(out, 0, sizeof(float), stream);
    if (useEf) {
        efrag_kernel<<<dim3((2 * Kn * Kn / 8) / 256), dim3(256), 0, stream>>>(
            trans, ef);
    }
    crf_main<<<dim3(2 * Bn), dim3(256), 0, stream>>>(
        inputs, tags, mask, useEf ? (const _Float16*)ef : nullptr,
        trans, start_t, end_t, out, aw, bw);
    merge_kernel<<<dim3(Bn), dim3(64), 0, stream>>>(aw, bw, out);
}

// Round 11
// 317.731 us; speedup vs baseline: 1.1113x; 1.0571x over previous
//
#include <hip/hip_runtime.h>
#include <hip/hip_fp16.h>

namespace {
constexpr int Bn = 64;
constexpr int Tn = 1024;
constexpr int Kn = 256;
constexpr int TH = 512;   // merge point: fwd computes alpha(TH), bwd beta(TH)

constexpr float LOG2E  = 1.4426950408889634f;
constexpr float LN2    = 0.6931471805599453f;
constexpr float RBIAS  = 4.0f;   // headroom: p = exp2(v - (max2 + RBIAS))
constexpr float PCLAMP = 15.5f;  // f16 overflow guard (prologue/masked path)
constexpr float VCLAMP = 60000.f; // f16 overflow guard (value domain)

typedef _Float16 half8 __attribute__((ext_vector_type(8)));
typedef float f32x4 __attribute__((ext_vector_type(4)));

// hardware base-2 transcendentals (v_exp_f32 / v_log_f32 ARE base-2 on gfx9)
__device__ __forceinline__ float fexp2(float x) {
    float r; asm("v_exp_f32 %0, %1" : "=v"(r) : "v"(x)); return r;
}
__device__ __forceinline__ float flog2(float x) {
    float r; asm("v_log_f32 %0, %1" : "=v"(r) : "v"(x)); return r;
}

// ---- DPP wave reductions ----
template <int C>
__device__ __forceinline__ float dppmax1(float x) {
    int o = __builtin_bit_cast(int, x);
    int y = __builtin_amdgcn_update_dpp(o, o, C, 0xF, 0xF, false);
    return fmaxf(x, __builtin_bit_cast(float, y));
}
template <int C>
__device__ __forceinline__ float dppadd1(float x) {
    int y = __builtin_amdgcn_update_dpp(0, __builtin_bit_cast(int, x), C, 0xF, 0xF, true);
    return x + __builtin_bit_cast(float, y);
}
__device__ __forceinline__ float wave_max64(float x) {
    x = dppmax1<0x111>(x);
    x = dppmax1<0x112>(x);
    x = dppmax1<0x114>(x);
    x = dppmax1<0x118>(x);
    x = dppmax1<0x142>(x);  // row_bcast:15
    x = dppmax1<0x143>(x);  // row_bcast:31
    return __builtin_bit_cast(float,
        __builtin_amdgcn_readlane(__builtin_bit_cast(int, x), 63));
}
__device__ __forceinline__ float wave_sum64(float x) {
    x = dppadd1<0x111>(x);
    x = dppadd1<0x112>(x);
    x = dppadd1<0x114>(x);
    x = dppadd1<0x118>(x);
    x = dppadd1<0x142>(x);
    x = dppadd1<0x143>(x);
    return __builtin_bit_cast(float,
        __builtin_amdgcn_readlane(__builtin_bit_cast(int, x), 63));
}
__device__ __forceinline__ float tree4(const f32x4 m) {
    return fmaxf(fmaxf(m[0], m[1]), fmaxf(m[2], m[3]));
}

// ---- pre-kernel: exp(trans) fragments, fwd (E) then bwd (E^T), 4-wave layout ----
__global__ __launch_bounds__(256) void efrag_kernel(
    const float* __restrict__ trans, _Float16* __restrict__ efrag)
{
    const int g   = blockIdx.x * 256 + threadIdx.x;   // 0..16383
    const int dir = g >> 13;
    const int gg  = g & 8191;
    const int l   = gg & 63;
    const int kt  = (gg >> 6) & 7;
    const int c   = (gg >> 9) & 3;
    const int wg  = (gg >> 11) & 3;
    const int n   = 64 * wg + 16 * c + (l & 15);
    const int k0  = 32 * kt + (l >> 4) * 8;
    half8 hb;
#pragma unroll
    for (int i = 0; i < 8; ++i) {
        const int k = k0 + i;
        hb[i] = (_Float16)__expf(dir == 0 ? trans[k * Kn + n]
                                          : trans[n * Kn + k]);
    }
    ((half8*)efrag)[g] = hb;
}

// 4-chain MFMA over the wave's 4 N-tiles, full K=256; af reused across tiles.
// Result: s = this lane's own column's sum (col j_own = 64wg + l).
#define MFMA32_SELECT()                                                          \
    const half8* prow = (const half8*)(&p_sh[PB][0]);                            \
    half8 af0 = prow[0 * 4 + La], af1 = prow[1 * 4 + La];                        \
    half8 af2 = prow[2 * 4 + La], af3 = prow[3 * 4 + La];                        \
    half8 af4 = prow[4 * 4 + La], af5 = prow[5 * 4 + La];                        \
    half8 af6 = prow[6 * 4 + La], af7 = prow[7 * 4 + La];                        \
    f32x4 a0 = __builtin_amdgcn_mfma_f32_16x16x32_f16(af0, Bfrag[0][0], zacc, 0, 0, 0); \
    f32x4 a1 = __builtin_amdgcn_mfma_f32_16x16x32_f16(af0, Bfrag[1][0], zacc, 0, 0, 0); \
    f32x4 a2 = __builtin_amdgcn_mfma_f32_16x16x32_f16(af0, Bfrag[2][0], zacc, 0, 0, 0); \
    f32x4 a3 = __builtin_amdgcn_mfma_f32_16x16x32_f16(af0, Bfrag[3][0], zacc, 0, 0, 0); \
    a0 = __builtin_amdgcn_mfma_f32_16x16x32_f16(af1, Bfrag[0][1], a0, 0, 0, 0);  \
    a1 = __builtin_amdgcn_mfma_f32_16x16x32_f16(af1, Bfrag[1][1], a1, 0, 0, 0);  \
    a2 = __builtin_amdgcn_mfma_f32_16x16x32_f16(af1, Bfrag[2][1], a2, 0, 0, 0);  \
    a3 = __builtin_amdgcn_mfma_f32_16x16x32_f16(af1, Bfrag[3][1], a3, 0, 0, 0);  \
    a0 = __builtin_amdgcn_mfma_f32_16x16x32_f16(af2, Bfrag[0][2], a0, 0, 0, 0);  \
    a1 = __builtin_amdgcn_mfma_f32_16x16x32_f16(af2, Bfrag[1][2], a1, 0, 0, 0);  \
    a2 = __builtin_amdgcn_mfma_f32_16x16x32_f16(af2, Bfrag[2][2], a2, 0, 0, 0);  \
    a3 = __builtin_amdgcn_mfma_f32_16x16x32_f16(af2, Bfrag[3][2], a3, 0, 0, 0);  \
    a0 = __builtin_amdgcn_mfma_f32_16x16x32_f16(af3, Bfrag[0][3], a0, 0, 0, 0);  \
    a1 = __builtin_amdgcn_mfma_f32_16x16x32_f16(af3, Bfrag[1][3], a1, 0, 0, 0);  \
    a2 = __builtin_amdgcn_mfma_f32_16x16x32_f16(af3, Bfrag[2][3], a2, 0, 0, 0);  \
    a3 = __builtin_amdgcn_mfma_f32_16x16x32_f16(af3, Bfrag[3][3], a3, 0, 0, 0);  \
    a0 = __builtin_amdgcn_mfma_f32_16x16x32_f16(af4, Bfrag[0][4], a0, 0, 0, 0);  \
    a1 = __builtin_amdgcn_mfma_f32_16x16x32_f16(af4, Bfrag[1][4], a1, 0, 0, 0);  \
    a2 = __builtin_amdgcn_mfma_f32_16x16x32_f16(af4, Bfrag[2][4], a2, 0, 0, 0);  \
    a3 = __builtin_amdgcn_mfma_f32_16x16x32_f16(af4, Bfrag[3][4], a3, 0, 0, 0);  \
    a0 = __builtin_amdgcn_mfma_f32_16x16x32_f16(af5, Bfrag[0][5], a0, 0, 0, 0);  \
    a1 = __builtin_amdgcn_mfma_f32_16x16x32_f16(af5, Bfrag[1][5], a1, 0, 0, 0);  \
    a2 = __builtin_amdgcn_mfma_f32_16x16x32_f16(af5, Bfrag[2][5], a2, 0, 0, 0);  \
    a3 = __builtin_amdgcn_mfma_f32_16x16x32_f16(af5, Bfrag[3][5], a3, 0, 0, 0);  \
    a0 = __builtin_amdgcn_mfma_f32_16x16x32_f16(af6, Bfrag[0][6], a0, 0, 0, 0);  \
    a1 = __builtin_amdgcn_mfma_f32_16x16x32_f16(af6, Bfrag[1][6], a1, 0, 0, 0);  \
    a2 = __builtin_amdgcn_mfma_f32_16x16x32_f16(af6, Bfrag[2][6], a2, 0, 0, 0);  \
    a3 = __builtin_amdgcn_mfma_f32_16x16x32_f16(af6, Bfrag[3][6], a3, 0, 0, 0);  \
    a0 = __builtin_amdgcn_mfma_f32_16x16x32_f16(af7, Bfrag[0][7], a0, 0, 0, 0);  \
    a1 = __builtin_amdgcn_mfma_f32_16x16x32_f16(af7, Bfrag[1][7], a1, 0, 0, 0);  \
    a2 = __builtin_amdgcn_mfma_f32_16x16x32_f16(af7, Bfrag[2][7], a2, 0, 0, 0);  \
    a3 = __builtin_amdgcn_mfma_f32_16x16x32_f16(af7, Bfrag[3][7], a3, 0, 0, 0);  \
    const float s01 = (La & 1) ? a1[0] : a0[0];                                  \
    const float s23 = (La & 1) ? a3[0] : a2[0];                                  \
    const float s   = (La & 2) ? s23 : s01;

// ---- fast step (fwd & bwd share the algebra) ----
// Publishes p(n) = s * 2^em(n) * 2^(R_prev - R_use)   [no log/exp on the
// critical path]. The value v(n) = sR + log2(s) + em (alpha for fwd, x for
// bwd) is computed LAZILY one step later, inside the MFMA shadow, for the
// 2-step-stale max tracking.
// Carried lag state: sR (R_prev at that step), s_save, em_save.
template <int PB, int NB, bool FWD>
__device__ __forceinline__ void fast_step(
    int tcur, float& R_prev, float& sR, float& s_save, float& em_save,
    float& lg1, float& lg2, float& lg3,
    const float* __restrict__ in_b, int j_own, int La, int wg,
    const half8 (&Bfrag)[4][8], const f32x4 zacc,
    _Float16 (*__restrict__ p_sh)[Kn], float (*__restrict__ Mv)[4])
{
    // ---- pre-barrier: prefetch rotate + per-element 2^em (all off-chain)
    const float em_C = lg1 * LOG2E;
    const float pe_C = fexp2(em_C);
    lg1 = lg2; lg2 = lg3;
    lg3 = in_b[(size_t)(FWD ? (tcur + 3) : (tcur - 3)) * Kn + j_own];

    asm volatile("s_waitcnt lgkmcnt(0)" ::: "memory");
    __builtin_amdgcn_s_barrier();
    __builtin_amdgcn_sched_barrier(0);

    // ---- post-barrier
    const f32x4 mv = *(const f32x4*)(&Mv[NB][0]);     // broadcast read
    const float R_use = tree4(mv) + RBIAS;
    const float sc2 = fexp2(R_prev - R_use);          // wave-uniform, off-chain

    MFMA32_SELECT()

    // lazy v(n-1) + max tracking (scheduled into the MFMA shadow)
    {
        const float v_prev = sR + flog2(s_save) + em_save;
        const float wmx = wave_max64(v_prev);
        Mv[PB][wg] = wmx;
    }

    // critical tail: two mults, clamp, cvt, write
    const float pv = fminf(s * pe_C * sc2, VCLAMP);
    p_sh[NB][j_own] = (_Float16)pv;

    // rotate lag state
    sR = R_prev; s_save = s; em_save = em_C;
    R_prev = R_use;
}

// ---- masked forward step (fallback path; direct computation) ----
template <int PB, int NB>
__device__ __forceinline__ void m_step(
    int tcur, float& alpha, float& R_prev,
    float& lg1, float& lg2, float& lg3,
    const float* __restrict__ in_b, int j_own, int La, int wg,
    const half8 (&Bfrag)[4][8], const f32x4 zacc,
    _Float16 (*__restrict__ p_sh)[Kn], float (*__restrict__ Mv)[4],
    const int* __restrict__ mask_sh)
{
    const float lgC = lg1; lg1 = lg2; lg2 = lg3;
    const int tp3 = (tcur + 3 < Tn) ? (tcur + 3) : (Tn - 1);
    lg3 = in_b[(size_t)tp3 * Kn + j_own];
    const int mkC = mask_sh[tcur];

    asm volatile("s_waitcnt lgkmcnt(0)" ::: "memory");
    __builtin_amdgcn_s_barrier();
    __builtin_amdgcn_sched_barrier(0);

    const f32x4 mv = *(const f32x4*)(&Mv[NB][0]);
    const float wmx = wave_max64(alpha);
    Mv[PB][wg] = wmx;
    const float R_use = tree4(mv) + RBIAS;

    MFMA32_SELECT()

    const float na = R_prev + flog2(s) + lgC * LOG2E;
    if (mkC > 0) alpha = na;
    const float pv = fexp2(fminf(alpha - R_use, PCLAMP));
    p_sh[NB][j_own] = (_Float16)pv;
    R_prev = R_use;
}

// ---- main kernel: one block per (chain, direction); 4 waves ----
__global__ __launch_bounds__(256, 1) void crf_main(
    const float* __restrict__ inputs,     // (B,T,K)
    const long long* __restrict__ tags,   // (B,T)
    const int* __restrict__ mask,         // (B,T)
    const _Float16* __restrict__ efrag,   // exp(trans) fragments (or null)
    const float* __restrict__ trans,      // (K,K)
    const float* __restrict__ start_t,    // (K,)
    const float* __restrict__ end_t,      // (K,)
    float* __restrict__ out,              // scalar (numerator accumulated here)
    float* __restrict__ aw,               // (B,K) alpha2(TH) out
    float* __restrict__ bw)               // (B,K) beta2(TH) out
{
    const int bid = blockIdx.x;
    const int b   = bid >> 1;
    const int dir = bid & 1;         // 0 = fwd, 1 = bwd
    const int tid = threadIdx.x;
    const int wg  = tid >> 6;        // wave 0..3, owns cols [64wg, 64wg+64)
    const int l   = tid & 63;
    const int La  = l >> 4;          // 0..3 (k-slice group / tile select)
    const int j_own = 64 * wg + l;   // every lane owns exactly one column

    __shared__ __align__(16) _Float16 p_sh[2][Kn];
    __shared__ __align__(16) float Mv[2][4];
    __shared__ int   mask_sh[Tn];
    __shared__ float sh_np;
    __shared__ int   sh_len;

    if (tid == 0) { sh_len = 0; sh_np = 0.f; }

    // ---- stage mask + length
    int cnt = 0;
    for (int t = tid; t < Tn; t += 256) {
        const int m = mask[b * Tn + t];
        mask_sh[t] = m;
        cnt += (m > 0) ? 1 : 0;
    }
    __syncthreads();
    {
        const float cf = wave_sum64((float)cnt);
        if (l == 0) atomicAdd(&sh_len, (int)(cf + 0.5f));
    }

    // ---- B-fragments: E for fwd, E^T for bwd; 4 N-tiles per wave
    half8 Bfrag[4][8];
    if (efrag != nullptr) {
        const half8* ef = (const half8*)efrag;
        const int base = dir * 8192;
#pragma unroll
        for (int c = 0; c < 4; ++c)
#pragma unroll
            for (int kt = 0; kt < 8; ++kt)
                Bfrag[c][kt] = ef[base + ((wg * 4 + c) * 8 + kt) * 64 + l];
    } else {
#pragma unroll
        for (int c = 0; c < 4; ++c) {
            const int n = 64 * wg + 16 * c + (l & 15);
#pragma unroll
            for (int kt = 0; kt < 8; ++kt) {
                const int k0 = 32 * kt + La * 8;
                half8 hb;
#pragma unroll
                for (int i = 0; i < 8; ++i) {
                    const int k = k0 + i;
                    hb[i] = (_Float16)__expf(dir == 0 ? trans[k * Kn + n]
                                                      : trans[n * Kn + k]);
                }
                Bfrag[c][kt] = hb;
            }
        }
    }

    const size_t bTK = (size_t)b * (size_t)(Tn * Kn);
    const float* in_b = inputs + bTK;
    const float endj  = end_t[j_own];

    f32x4 zacc = {0.f, 0.f, 0.f, 0.f};
    asm volatile("" : "+v"(zacc));

    // ---- direction-specific init (own column only)
    // v0 = alpha(0) for fwd; x(1023) = beta(1023)+em(1023) for bwd
    float v0 = 0.f;
    float lg1 = 0.f, lg2 = 0.f, lg3 = 0.f;
    if (dir == 0) {
        v0  = (in_b[j_own] + start_t[j_own]) * LOG2E;
        lg1 = in_b[1 * Kn + j_own];
        lg2 = in_b[2 * Kn + j_own];
        lg3 = in_b[3 * Kn + j_own];
    } else {
        v0  = endj * LOG2E + in_b[(size_t)(Tn - 1) * Kn + j_own] * LOG2E;
        lg1 = in_b[(size_t)(Tn - 2) * Kn + j_own];
        lg2 = in_b[(size_t)(Tn - 3) * Kn + j_own];
        lg3 = in_b[(size_t)(Tn - 4) * Kn + j_own];
    }
    Mv[1][wg] = wave_max64(v0);
    __syncthreads();
    const int end_idx = sh_len - 1;

    float R_prev;
    {
        R_prev = tree4(*(const f32x4*)(&Mv[1][0])) + RBIAS;
        const float pv = fexp2(fminf(v0 - R_prev, PCLAMP));
        p_sh[0][j_own] = (_Float16)pv;
    }

    if (sh_len == Tn) {
        // lag seeds: v_prev formula sR + log2(s_save) + em_save must yield v0
        float sR = v0, s_save = 1.0f, em_save = 0.0f;
        if (dir == 0) {
            // fwd: steps t = 1..512 -> alpha2(512)
            for (int t = 1; t <= TH; t += 2) {
                fast_step<0, 1, true>(t,     R_prev, sR, s_save, em_save,
                                      lg1, lg2, lg3, in_b, j_own, La, wg,
                                      Bfrag, zacc, p_sh, Mv);
                fast_step<1, 0, true>(t + 1, R_prev, sR, s_save, em_save,
                                      lg1, lg2, lg3, in_b, j_own, La, wg,
                                      Bfrag, zacc, p_sh, Mv);
            }
            // alpha(512) = sR + log2(s(512)) + em(512)
            aw[b * Kn + j_own] = sR + flog2(s_save) + em_save;
        } else {
            // bwd: steps tcur = 1022..512 (511 steps) -> beta2(512)
            fast_step<0, 1, false>(1022, R_prev, sR, s_save, em_save,
                                   lg1, lg2, lg3, in_b, j_own, La, wg,
                                   Bfrag, zacc, p_sh, Mv);
            for (int t = 1021; t >= 513; t -= 2) {
                fast_step<1, 0, false>(t,     R_prev, sR, s_save, em_save,
                                       lg1, lg2, lg3, in_b, j_own, La, wg,
                                       Bfrag, zacc, p_sh, Mv);
                fast_step<0, 1, false>(t - 1, R_prev, sR, s_save, em_save,
                                       lg1, lg2, lg3, in_b, j_own, La, wg,
                                       Bfrag, zacc, p_sh, Mv);
            }
            // beta(512) = sR + log2(s(512))   [em of t=512 NOT folded]
            bw[b * Kn + j_own] = sR + flog2(s_save);
        }
    } else {
        if (dir == 0) {
            // masked fallback: full 1023-step chain; fold end_t before writing
            float alpha = v0;
            m_step<0, 1>(1, alpha, R_prev, lg1, lg2, lg3, in_b, j_own, La, wg,
                         Bfrag, zacc, p_sh, Mv, mask_sh);
            for (int t = 2; t < Tn; t += 2) {
                m_step<1, 0>(t,     alpha, R_prev, lg1, lg2, lg3, in_b, j_own, La,
                             wg, Bfrag, zacc, p_sh, Mv, mask_sh);
                m_step<0, 1>(t + 1, alpha, R_prev, lg1, lg2, lg3, in_b, j_own, La,
                             wg, Bfrag, zacc, p_sh, Mv, mask_sh);
            }
            aw[b * Kn + j_own] = alpha + endj * LOG2E;
        } else {
            // masked bwd: identity contribution
            bw[b * Kn + tid] = 0.f;
            return;
        }
    }

    // ---- numerator: fwd block only
    if (dir == 0) {
        float np = 0.f;
        for (int t = tid; t < Tn; t += 256) {
            const int   tg = (int)tags[b * Tn + t];
            const float e  = in_b[(size_t)t * Kn + tg];
            if (t == 0) {
                np += e + start_t[tg];
            } else {
                const float mf = (float)mask_sh[t];
                const int   tq = (int)tags[b * Tn + t - 1];
                np += mf * (e + trans[tq * Kn + tg]);
            }
        }
        np = wave_sum64(np);
        if (l == 0) atomicAdd(&sh_np, np);
        __syncthreads();
        if (tid == 0) {
            atomicAdd(out, sh_np + end_t[(int)tags[b * Tn + end_idx]]);
        }
    }
}

// ---- merge kernel: denom_b = ln2 * LSE2_j(alpha2[b][j] + beta2[b][j]) ----
__global__ __launch_bounds__(64) void merge_kernel(
    const float* __restrict__ aw, const float* __restrict__ bw,
    float* __restrict__ out)
{
    const int b = blockIdx.x;
    const int l = threadIdx.x;
    const f32x4 va = *(const f32x4*)(aw + b * Kn + 4 * l);
    const f32x4 vb = *(const f32x4*)(bw + b * Kn + 4 * l);
    const float v0 = va[0] + vb[0];
    const float v1 = va[1] + vb[1];
    const float v2 = va[2] + vb[2];
    const float v3 = va[3] + vb[3];
    float m = fmaxf(fmaxf(v0, v1), fmaxf(v2, v3));
    m = wave_max64(m);
    float S = fexp2(v0 - m) + fexp2(v1 - m) + fexp2(v2 - m) + fexp2(v3 - m);
    S = wave_sum64(S);
    if (l == 0) atomicAdd(out, -(LN2 * (m + flog2(S))));
}

}  // namespace

extern "C" void kernel_launch(void* const* d_in, const int* in_sizes, int n_in,
                              void* d_out, int out_size, void* d_ws, size_t ws_size,
                              hipStream_t stream) {
    const float*     inputs  = (const float*)d_in[0];
    const long long* tags    = (const long long*)d_in[1];
    const int*       mask    = (const int*)d_in[2];
    const float*     trans   = (const float*)d_in[3];
    const float*     start_t = (const float*)d_in[4];
    const float*     end_t   = (const float*)d_in[5];
    float* out = (float*)d_out;

    // workspace layout: aw (B*K f32) | bw (B*K f32) | efrag (2*K*K f16)
    float*    aw = (float*)d_ws;
    float*    bw = aw + Bn * Kn;
    _Float16* ef = (_Float16*)(bw + Bn * Kn);
    const size_t need_vec = (size_t)2 * Bn * Kn * sizeof(float);          // 128 KiB
    const size_t need_ef  = need_vec + (size_t)2 * Kn * Kn * sizeof(_Float16);
    const bool useEf = (d_ws != nullptr) && (ws_size >= need_ef);

    (void)hipMemsetAsync(out, 0, sizeof(float), stream);
    if (useEf) {
        efrag_kernel<<<dim3((2 * Kn * Kn / 8) / 256), dim3(256), 0, stream>>>(
            trans, ef);
    }
    crf_main<<<dim3(2 * Bn), dim3(256), 0, stream>>>(
        inputs, tags, mask, useEf ? (const _Float16*)ef : nullptr,
        trans, start_t, end_t, out, aw, bw);
    merge_kernel<<<dim3(Bn), dim3(64), 0, stream>>>(aw, bw, out);
}